// Round 8
// baseline (28.420 us; speedup 1.0000x reference)
//
#include <hip/hip_runtime.h>

// ClipCluLoss: inputs [B=1024, T=32, D=1024] fp32 -> scalar fp32.
// dist[b] = T - (1/T) * || sum_t x_n[b,t,:] ||^2 ; out = mean_b dist[b].
//
// Two kernels (coop grid-sync: +65us; ticket fence+atomic: +35us — both
// measured FAR worse than the ~3us kernel2 tail).
//
// kernel1: 512 blocks x 512 threads, 2 samples/block (b, b+512), all
// blocks co-resident (2/CU) => single ramp. Sample-1 loads are issued
// before sample-0's LDS epilogue so the epilogue hides the HBM latency.
// Wave w owns rows w*4..w*4+3 (norm butterfly wave-local). Lane l owns
// cols {i*256+l*4}: every load is a contiguous 1 KB wave transaction.

#define TT 32
#define DD 1024
#define BB 1024
#define GRID 512

#define PIN4(f4) \
  asm volatile("" : "+v"((f4).x), "+v"((f4).y), "+v"((f4).z), "+v"((f4).w))

__global__ __launch_bounds__(512, 4) void clip_partial_kernel(
    const float* __restrict__ x, float* __restrict__ partial) {
  const int lane = threadIdx.x & 63;
  const int wave = threadIdx.x >> 6;  // 0..7

  __shared__ float4 sacc[8 * 4 * 64];  // 32 KB: [wave][chunk][lane]
  __shared__ float wsum[4];

  const int b0 = blockIdx.x;
  const int b1 = blockIdx.x + GRID;
  const float* __restrict__ xb0 = x + (size_t)b0 * (TT * DD);
  const float* __restrict__ xb1 = x + (size_t)b1 * (TT * DD);

  // ---- Sample 0 loads: 4 rows x 4 chunks of float4, coalesced. Pin so the
  // compiler can't rematerialize (measured: without pin VGPR=40 => 2 reads).
  float4 v[4][4];
#pragma unroll
  for (int r = 0; r < 4; ++r)
#pragma unroll
    for (int i = 0; i < 4; ++i)
      v[r][i] = *reinterpret_cast<const float4*>(xb0 + (wave * 4 + r) * DD +
                                                 i * 256 + lane * 4);
#pragma unroll
  for (int r = 0; r < 4; ++r)
#pragma unroll
    for (int i = 0; i < 4; ++i) PIN4(v[r][i]);

  // ---- Norms + weighted column sums for sample 0.
  float inv[4];
#pragma unroll
  for (int r = 0; r < 4; ++r) {
    float ss = 0.0f;
#pragma unroll
    for (int i = 0; i < 4; ++i)
      ss += v[r][i].x * v[r][i].x + v[r][i].y * v[r][i].y +
            v[r][i].z * v[r][i].z + v[r][i].w * v[r][i].w;
#pragma unroll
    for (int off = 32; off; off >>= 1) ss += __shfl_xor(ss, off);
    inv[r] = 1.0f / fmaxf(sqrtf(ss), 1e-12f);
  }
  float4 a[4];
#pragma unroll
  for (int i = 0; i < 4; ++i) {
    a[i] = make_float4(0.f, 0.f, 0.f, 0.f);
#pragma unroll
    for (int r = 0; r < 4; ++r) {
      a[i].x = fmaf(v[r][i].x, inv[r], a[i].x);
      a[i].y = fmaf(v[r][i].y, inv[r], a[i].y);
      a[i].z = fmaf(v[r][i].z, inv[r], a[i].z);
      a[i].w = fmaf(v[r][i].w, inv[r], a[i].w);
    }
  }

  // ---- PREFETCH sample 1 now (v dead): latency hides under the epilogue.
#pragma unroll
  for (int r = 0; r < 4; ++r)
#pragma unroll
    for (int i = 0; i < 4; ++i)
      v[r][i] = *reinterpret_cast<const float4*>(xb1 + (wave * 4 + r) * DD +
                                                 i * 256 + lane * 4);

  // ---- Epilogue for sample 0 (runs while prefetch is in flight).
#pragma unroll
  for (int i = 0; i < 4; ++i) sacc[(wave * 4 + i) * 64 + lane] = a[i];
  __syncthreads();
  {
    float local = 0.0f;
    if (threadIdx.x < 256) {
      const int i = threadIdx.x >> 6;
      float4 s4 = make_float4(0.f, 0.f, 0.f, 0.f);
#pragma unroll
      for (int w = 0; w < 8; ++w) {
        const float4 t4 = sacc[(w * 4 + i) * 64 + lane];
        s4.x += t4.x;
        s4.y += t4.y;
        s4.z += t4.z;
        s4.w += t4.w;
      }
      local = s4.x * s4.x + s4.y * s4.y + s4.z * s4.z + s4.w * s4.w;
    }
#pragma unroll
    for (int off = 32; off; off >>= 1) local += __shfl_xor(local, off);
    if (wave < 4 && lane == 0) wsum[wave] = local;
    __syncthreads();  // wsum ready; also gates sacc reuse below
    if (threadIdx.x == 0)
      partial[b0] =
          (float)TT - (wsum[0] + wsum[1] + wsum[2] + wsum[3]) / (float)TT;
  }

  // ---- Sample 1: pin AFTER the epilogue (a pin at issue would force a
  // vmcnt(0) drain and kill the overlap), then same pipeline.
#pragma unroll
  for (int r = 0; r < 4; ++r)
#pragma unroll
    for (int i = 0; i < 4; ++i) PIN4(v[r][i]);

#pragma unroll
  for (int r = 0; r < 4; ++r) {
    float ss = 0.0f;
#pragma unroll
    for (int i = 0; i < 4; ++i)
      ss += v[r][i].x * v[r][i].x + v[r][i].y * v[r][i].y +
            v[r][i].z * v[r][i].z + v[r][i].w * v[r][i].w;
#pragma unroll
    for (int off = 32; off; off >>= 1) ss += __shfl_xor(ss, off);
    inv[r] = 1.0f / fmaxf(sqrtf(ss), 1e-12f);
  }
#pragma unroll
  for (int i = 0; i < 4; ++i) {
    a[i] = make_float4(0.f, 0.f, 0.f, 0.f);
#pragma unroll
    for (int r = 0; r < 4; ++r) {
      a[i].x = fmaf(v[r][i].x, inv[r], a[i].x);
      a[i].y = fmaf(v[r][i].y, inv[r], a[i].y);
      a[i].z = fmaf(v[r][i].z, inv[r], a[i].z);
      a[i].w = fmaf(v[r][i].w, inv[r], a[i].w);
    }
  }
#pragma unroll
  for (int i = 0; i < 4; ++i) sacc[(wave * 4 + i) * 64 + lane] = a[i];
  __syncthreads();
  {
    float local = 0.0f;
    if (threadIdx.x < 256) {
      const int i = threadIdx.x >> 6;
      float4 s4 = make_float4(0.f, 0.f, 0.f, 0.f);
#pragma unroll
      for (int w = 0; w < 8; ++w) {
        const float4 t4 = sacc[(w * 4 + i) * 64 + lane];
        s4.x += t4.x;
        s4.y += t4.y;
        s4.z += t4.z;
        s4.w += t4.w;
      }
      local = s4.x * s4.x + s4.y * s4.y + s4.z * s4.z + s4.w * s4.w;
    }
#pragma unroll
    for (int off = 32; off; off >>= 1) local += __shfl_xor(local, off);
    if (wave < 4 && lane == 0) wsum[wave] = local;
    __syncthreads();
    if (threadIdx.x == 0)
      partial[b1] =
          (float)TT - (wsum[0] + wsum[1] + wsum[2] + wsum[3]) / (float)TT;
  }
}

__global__ __launch_bounds__(256) void clip_reduce_kernel(
    const float* __restrict__ partial, float* __restrict__ out) {
  const int lane = threadIdx.x & 63;
  const int wave = threadIdx.x >> 6;
  const float4 v =
      *reinterpret_cast<const float4*>(partial + threadIdx.x * 4);
  float s = v.x + v.y + v.z + v.w;
#pragma unroll
  for (int off = 32; off; off >>= 1) s += __shfl_xor(s, off);
  __shared__ float wsum[4];
  if (lane == 0) wsum[wave] = s;
  __syncthreads();
  if (threadIdx.x == 0)
    out[0] = (wsum[0] + wsum[1] + wsum[2] + wsum[3]) * (1.0f / (float)BB);
}

extern "C" void kernel_launch(void* const* d_in, const int* in_sizes, int n_in,
                              void* d_out, int out_size, void* d_ws,
                              size_t ws_size, hipStream_t stream) {
  const float* x = (const float*)d_in[0];
  float* partial = (float*)d_ws;  // 1024 floats = 4 KB scratch
  float* out = (float*)d_out;

  clip_partial_kernel<<<GRID, 512, 0, stream>>>(x, partial);
  clip_reduce_kernel<<<1, 256, 0, stream>>>(partial, out);
}

// Round 9
// 25.509 us; speedup vs baseline: 1.1141x; 1.1141x over previous
//
#include <hip/hip_runtime.h>

// ClipCluLoss: inputs [B=1024, T=32, D=1024] fp32 -> scalar fp32.
// dist[b] = T - (1/T) * || sum_t x_n[b,t,:] ||^2 ; out = mean_b dist[b].
//
// Structure history (measured):
//   two-kernel, reg-resident tile, 512thr/block ............ 27.75 us (best)
//   coop grid-sync fusion ................................... 93.7 us (FAIL)
//   ticket fence+atomic fusion .............................. 62.9 us (FAIL)
//   2 samples/block + cross-sample prefetch ................. 28.4 us (worse)
// This round: R7 structure + NONTEMPORAL loads (read-once stream, no reuse
// => bypass cache allocation; nt bit on global_load_dwordx4).

#define TT 32
#define DD 1024
#define BB 1024

typedef float f32x4 __attribute__((ext_vector_type(4)));

__device__ __forceinline__ float4 ld_nt(const float* p) {
  const f32x4 t = __builtin_nontemporal_load(reinterpret_cast<const f32x4*>(p));
  return make_float4(t[0], t[1], t[2], t[3]);
}

#define PIN4(f4) \
  asm volatile("" : "+v"((f4).x), "+v"((f4).y), "+v"((f4).z), "+v"((f4).w))

__global__ __launch_bounds__(512, 4) void clip_partial_kernel(
    const float* __restrict__ x, float* __restrict__ partial) {
  const int b = blockIdx.x;
  const float* __restrict__ xb = x + (size_t)b * (TT * DD);
  const int lane = threadIdx.x & 63;
  const int wave = threadIdx.x >> 6;  // 0..7

  __shared__ float4 sacc[8 * 4 * 64];  // 32 KB: [wave][chunk][lane]
  __shared__ float wsum[4];

  // ---- Load slice: 4 rows x 4 chunks of float4, coalesced, NONTEMPORAL.
  float4 v[4][4];
#pragma unroll
  for (int r = 0; r < 4; ++r)
#pragma unroll
    for (int i = 0; i < 4; ++i)
      v[r][i] = ld_nt(xb + (wave * 4 + r) * DD + i * 256 + lane * 4);

  // ---- Anti-remat pin: without it the compiler reloads the tile from
  // memory for the second consumer (measured VGPR=40 => double read).
#pragma unroll
  for (int r = 0; r < 4; ++r)
#pragma unroll
    for (int i = 0; i < 4; ++i) PIN4(v[r][i]);

  // ---- Row norms (wave-local; butterfly leaves the sum in every lane).
  float inv[4];
#pragma unroll
  for (int r = 0; r < 4; ++r) {
    float ss = 0.0f;
#pragma unroll
    for (int i = 0; i < 4; ++i)
      ss += v[r][i].x * v[r][i].x + v[r][i].y * v[r][i].y +
            v[r][i].z * v[r][i].z + v[r][i].w * v[r][i].w;
#pragma unroll
    for (int off = 32; off; off >>= 1) ss += __shfl_xor(ss, off);
    inv[r] = 1.0f / fmaxf(sqrtf(ss), 1e-12f);
  }

  // ---- Per-wave weighted column sums (registers only).
#pragma unroll
  for (int i = 0; i < 4; ++i) {
    float4 a = make_float4(0.f, 0.f, 0.f, 0.f);
#pragma unroll
    for (int r = 0; r < 4; ++r) {
      a.x = fmaf(v[r][i].x, inv[r], a.x);
      a.y = fmaf(v[r][i].y, inv[r], a.y);
      a.z = fmaf(v[r][i].z, inv[r], a.z);
      a.w = fmaf(v[r][i].w, inv[r], a.w);
    }
    sacc[(wave * 4 + i) * 64 + lane] = a;
  }
  __syncthreads();

  // ---- Combine the 8 wave-partials per column, square, block-reduce.
  float local = 0.0f;
  if (threadIdx.x < 256) {
    const int i = threadIdx.x >> 6;
    float4 s4 = make_float4(0.f, 0.f, 0.f, 0.f);
#pragma unroll
    for (int w = 0; w < 8; ++w) {
      const float4 t4 = sacc[(w * 4 + i) * 64 + lane];
      s4.x += t4.x;
      s4.y += t4.y;
      s4.z += t4.z;
      s4.w += t4.w;
    }
    local = s4.x * s4.x + s4.y * s4.y + s4.z * s4.z + s4.w * s4.w;
  }
#pragma unroll
  for (int off = 32; off; off >>= 1) local += __shfl_xor(local, off);
  if (wave < 4 && lane == 0) wsum[wave] = local;
  __syncthreads();
  if (threadIdx.x == 0) {
    const float s2 = wsum[0] + wsum[1] + wsum[2] + wsum[3];
    partial[b] = (float)TT - s2 * (1.0f / (float)TT);
  }
}

__global__ __launch_bounds__(256) void clip_reduce_kernel(
    const float* __restrict__ partial, float* __restrict__ out) {
  const int lane = threadIdx.x & 63;
  const int wave = threadIdx.x >> 6;
  const float4 v =
      *reinterpret_cast<const float4*>(partial + threadIdx.x * 4);
  float s = v.x + v.y + v.z + v.w;
#pragma unroll
  for (int off = 32; off; off >>= 1) s += __shfl_xor(s, off);
  __shared__ float wsum[4];
  if (lane == 0) wsum[wave] = s;
  __syncthreads();
  if (threadIdx.x == 0)
    out[0] = (wsum[0] + wsum[1] + wsum[2] + wsum[3]) * (1.0f / (float)BB);
}

extern "C" void kernel_launch(void* const* d_in, const int* in_sizes, int n_in,
                              void* d_out, int out_size, void* d_ws,
                              size_t ws_size, hipStream_t stream) {
  const float* x = (const float*)d_in[0];
  float* partial = (float*)d_ws;  // 1024 floats = 4 KB scratch
  float* out = (float*)d_out;

  clip_partial_kernel<<<BB, 512, 0, stream>>>(x, partial);
  clip_reduce_kernel<<<1, 256, 0, stream>>>(partial, out);
}